// Round 1
// 2195.255 us; speedup vs baseline: 1.1375x; 1.1375x over previous
//
#include <hip/hip_runtime.h>
#include <cmath>

#define LDSK 40   // padded LDS row stride (bf16 elems) for MFMA tiles

typedef __attribute__((ext_vector_type(4))) float floatx4;
typedef __attribute__((ext_vector_type(8))) short shortx8;
typedef __attribute__((ext_vector_type(4))) short shortx4;

constexpr int cB = 2, cS = 1024, cH = 2048, cNH = 16, cNKV = 4, cHD = 128, cF = 4096;
constexpr int cT = cB * cS;

// ---------- bf16 conversion (RNE) ----------
__device__ __forceinline__ unsigned short f2bf(float f) {
  union { float f; unsigned u; } v; v.f = f;
  unsigned r = v.u + 0x7FFFu + ((v.u >> 16) & 1u);
  return (unsigned short)(r >> 16);
}
__device__ __forceinline__ shortx4 f2bf4(float a, float b, float c, float d) {
  shortx4 s;
  s.x = (short)f2bf(a); s.y = (short)f2bf(b);
  s.z = (short)f2bf(c); s.w = (short)f2bf(d);
  return s;
}

// ====================================================================
// fp32 vector GEMM (pre-gate path: must track numpy fp32 to ~1e-5)
// 64x64 tile, BK=16, 256 threads, 4x4 per thread
// ====================================================================
template <int EPI>  // 0 none, 1 +bias, 2 +bias+resid
__global__ __launch_bounds__(256) void gemm32(const float* __restrict__ A,
                                              const float* __restrict__ B,
                                              float* __restrict__ C,
                                              const float* __restrict__ bias,
                                              const float* __restrict__ resid,
                                              int K, long lda, long ldb, long ldc) {
  __shared__ __align__(16) float As[16][68];
  __shared__ __align__(16) float Bs[16][68];
  int tid = threadIdx.x;
  int m0 = blockIdx.y * 64, n0 = blockIdx.x * 64;
  float acc[4][4] = {};
  int ty = tid >> 4, tx = tid & 15;
  for (int k0 = 0; k0 < K; k0 += 16) {
#pragma unroll
    for (int it = 0; it < 4; ++it) {
      int idx = tid + it * 256;
      int m = idx >> 4, k = idx & 15;
      As[k][m] = A[(long)(m0 + m) * lda + k0 + k];
      int n = idx & 63, kb = idx >> 6;
      Bs[kb][n] = B[(long)(k0 + kb) * ldb + n0 + n];
    }
    __syncthreads();
#pragma unroll
    for (int k = 0; k < 16; ++k) {
      float4 av = *(const float4*)&As[k][ty * 4];
      float4 bv = *(const float4*)&Bs[k][tx * 4];
      float a4[4] = {av.x, av.y, av.z, av.w};
      float b4[4] = {bv.x, bv.y, bv.z, bv.w};
#pragma unroll
      for (int i = 0; i < 4; ++i)
#pragma unroll
        for (int j = 0; j < 4; ++j) acc[i][j] += a4[i] * b4[j];
    }
    __syncthreads();
  }
#pragma unroll
  for (int i = 0; i < 4; ++i)
#pragma unroll
    for (int j = 0; j < 4; ++j) {
      int gr = m0 + ty * 4 + i, gc = n0 + tx * 4 + j;
      float val = acc[i][j];
      if (EPI >= 1) val += bias[gc];
      if (EPI == 2) val += resid[(long)gr * ldc + gc];
      C[(long)gr * ldc + gc] = val;
    }
}

// ---------- QK^T (fp32), per head, one batch; causal tile skip ----------
__global__ __launch_bounds__(256) void qk32(const float* __restrict__ q,
                                            const float* __restrict__ kx,
                                            float* __restrict__ sc, int b) {
  if ((int)blockIdx.x > (int)blockIdx.y) return;
  int h = blockIdx.z, hk = h >> 2;
  int m0 = blockIdx.y * 64, n0 = blockIdx.x * 64;
  const float* Aq = q + (long)b * cS * (cNH * cHD) + h * cHD + (long)m0 * (cNH * cHD);
  const float* Bk = kx + (long)b * cS * (cNKV * cHD) + hk * cHD + (long)n0 * (cNKV * cHD);
  float* Cb = sc + (long)h * cS * cS;
  __shared__ __align__(16) float As[16][68];
  __shared__ __align__(16) float Bs[16][68];
  int tid = threadIdx.x;
  float acc[4][4] = {};
  int ty = tid >> 4, tx = tid & 15;
  for (int k0 = 0; k0 < cHD; k0 += 16) {
#pragma unroll
    for (int it = 0; it < 4; ++it) {
      int idx = tid + it * 256;
      int r = idx >> 4, k = idx & 15;
      As[k][r] = Aq[(long)r * (cNH * cHD) + k0 + k];
      Bs[k][r] = Bk[(long)r * (cNKV * cHD) + k0 + k];
    }
    __syncthreads();
#pragma unroll
    for (int k = 0; k < 16; ++k) {
      float4 av = *(const float4*)&As[k][ty * 4];
      float4 bv = *(const float4*)&Bs[k][tx * 4];
      float a4[4] = {av.x, av.y, av.z, av.w};
      float b4[4] = {bv.x, bv.y, bv.z, bv.w};
#pragma unroll
      for (int i = 0; i < 4; ++i)
#pragma unroll
        for (int j = 0; j < 4; ++j) acc[i][j] += a4[i] * b4[j];
    }
    __syncthreads();
  }
#pragma unroll
  for (int i = 0; i < 4; ++i)
#pragma unroll
    for (int j = 0; j < 4; ++j)
      Cb[(long)(m0 + ty * 4 + i) * cS + n0 + tx * 4 + j] = acc[i][j];
}

// ---------- causal softmax, fp32, IN PLACE on sc (scale fused) ----------
__global__ __launch_bounds__(256) void softmax32(float* __restrict__ sc,
                                                 const int* __restrict__ amask, int b) {
  int row = blockIdx.x;          // h*1024 + q
  int qi = row & (cS - 1);
  float* sr = sc + (long)row * cS;
  int tid = threadIdx.x;
  const float scale = 0.08838834764831845f;  // 1/sqrt(128)
  float4 vv = *(const float4*)(sr + tid * 4);
  float va[4] = {vv.x, vv.y, vv.z, vv.w};
  bool ok[4];
  float mx = -INFINITY;
#pragma unroll
  for (int c = 0; c < 4; ++c) {
    int j = tid * 4 + c;
    ok[c] = (j <= qi) && (amask[b * cS + j] > 0);
    va[c] = ok[c] ? va[c] * scale : -INFINITY;
    mx = fmaxf(mx, va[c]);
  }
#pragma unroll
  for (int off = 32; off; off >>= 1) mx = fmaxf(mx, __shfl_down(mx, off));
  __shared__ float r4[4], s4[4];
  if ((tid & 63) == 0) r4[tid >> 6] = mx;
  __syncthreads();
  mx = fmaxf(fmaxf(r4[0], r4[1]), fmaxf(r4[2], r4[3]));
  float ev[4], sum = 0.f;
#pragma unroll
  for (int c = 0; c < 4; ++c) {
    ev[c] = ok[c] ? expf(va[c] - mx) : 0.f;
    sum += ev[c];
  }
#pragma unroll
  for (int off = 32; off; off >>= 1) sum += __shfl_down(sum, off);
  if ((tid & 63) == 0) s4[tid >> 6] = sum;
  __syncthreads();
  sum = s4[0] + s4[1] + s4[2] + s4[3];
  float inv = 1.f / sum;
  float4 r;
  r.x = ev[0] * inv; r.y = ev[1] * inv; r.z = ev[2] * inv; r.w = ev[3] * inv;
  *(float4*)(sr + tid * 4) = r;
}

// ---------- P @ V (fp32), per head, one batch; k-range trimmed ----------
__global__ __launch_bounds__(256) void pv32(const float* __restrict__ P,
                                            const float* __restrict__ v,
                                            float* __restrict__ attn, int b) {
  int h = blockIdx.z, hk = h >> 2;
  int m0 = blockIdx.y * 64, n0 = blockIdx.x * 64;
  const float* Pr = P + (long)h * cS * cS + (long)m0 * cS;
  const float* Vb = v + (long)b * cS * (cNKV * cHD) + hk * cHD;
  float* Cb = attn + (long)b * cS * (cNH * cHD) + h * cHD;
  __shared__ __align__(16) float As[16][68];
  __shared__ __align__(16) float Bs[16][68];
  int tid = threadIdx.x;
  float acc[4][4] = {};
  int ty = tid >> 4, tx = tid & 15;
  int kend = m0 + 64;  // probs are exactly 0 beyond the causal diagonal
  for (int k0 = 0; k0 < kend; k0 += 16) {
#pragma unroll
    for (int it = 0; it < 4; ++it) {
      int idx = tid + it * 256;
      int m = idx >> 4, k = idx & 15;
      As[k][m] = Pr[(long)m * cS + k0 + k];
      int n = idx & 63, kb = idx >> 6;
      Bs[kb][n] = Vb[(long)(k0 + kb) * (cNKV * cHD) + n0 + n];
    }
    __syncthreads();
#pragma unroll
    for (int k = 0; k < 16; ++k) {
      float4 av = *(const float4*)&As[k][ty * 4];
      float4 bv = *(const float4*)&Bs[k][tx * 4];
      float a4[4] = {av.x, av.y, av.z, av.w};
      float b4[4] = {bv.x, bv.y, bv.z, bv.w};
#pragma unroll
      for (int i = 0; i < 4; ++i)
#pragma unroll
        for (int j = 0; j < 4; ++j) acc[i][j] += a4[i] * b4[j];
    }
    __syncthreads();
  }
#pragma unroll
  for (int i = 0; i < 4; ++i)
#pragma unroll
    for (int j = 0; j < 4; ++j)
      Cb[(long)(m0 + ty * 4 + i) * (cNH * cHD) + n0 + tx * 4 + j] = acc[i][j];
}

// ---------- LayerNorm (fp32, one block per token) ----------
__global__ __launch_bounds__(256) void ln_kernel(const float* __restrict__ in,
                                                 const float* __restrict__ w,
                                                 const float* __restrict__ b,
                                                 float* __restrict__ out) {
  int t = blockIdx.x, tid = threadIdx.x;
  const float* xr = in + (long)t * cH;
  float* yr = out + (long)t * cH;
  float4 v0 = *(const float4*)(xr + tid * 4);
  float4 v1 = *(const float4*)(xr + 1024 + tid * 4);
  float s1 = v0.x + v0.y + v0.z + v0.w + v1.x + v1.y + v1.z + v1.w;
  float s2 = v0.x * v0.x + v0.y * v0.y + v0.z * v0.z + v0.w * v0.w +
             v1.x * v1.x + v1.y * v1.y + v1.z * v1.z + v1.w * v1.w;
#pragma unroll
  for (int off = 32; off; off >>= 1) {
    s1 += __shfl_down(s1, off);
    s2 += __shfl_down(s2, off);
  }
  __shared__ float rs1[4], rs2[4];
  if ((tid & 63) == 0) { rs1[tid >> 6] = s1; rs2[tid >> 6] = s2; }
  __syncthreads();
  float ts1 = rs1[0] + rs1[1] + rs1[2] + rs1[3];
  float ts2 = rs2[0] + rs2[1] + rs2[2] + rs2[3];
  float mu = ts1 * (1.f / 2048.f);
  float var = ts2 * (1.f / 2048.f) - mu * mu;
  float rstd = rsqrtf(var + 1e-5f);
#pragma unroll
  for (int half = 0; half < 2; ++half) {
    int bi = tid * 4 + half * 1024;
    float4 vv = half ? v1 : v0;
    float4 wv4 = *(const float4*)(w + bi);
    float4 bv4 = *(const float4*)(b + bi);
    float4 r;
    r.x = (vv.x - mu) * rstd * wv4.x + bv4.x;
    r.y = (vv.y - mu) * rstd * wv4.y + bv4.y;
    r.z = (vv.z - mu) * rstd * wv4.z + bv4.z;
    r.w = (vv.w - mu) * rstd * wv4.w + bv4.w;
    *(float4*)(yr + bi) = r;
  }
}

// ---------- RoPE (fp32, in place; one wave per (token, head)) ----------
__global__ __launch_bounds__(256) void rope_kernel(float* __restrict__ x,
                                                   const int* __restrict__ pos, int nheads) {
  int row = blockIdx.x * 4 + (threadIdx.x >> 6);
  int lane = threadIdx.x & 63;
  int t = row / nheads;
  float* p = x + (long)row * cHD;
  float ang = (float)pos[t] * exp2f(-(float)lane * (19.931568569324174f / 64.f));
  float s, c;
  sincosf(ang, &s, &c);
  float lo = p[lane], hi = p[lane + 64];
  p[lane] = lo * c - hi * s;
  p[lane + 64] = hi * c + lo * s;
}

// ---------- router: fp32 logits + top-2 + softmax; expert lists ----------
__global__ void zero_cnt(int* c) {
  if (threadIdx.x < 8) c[threadIdx.x] = 0;
}
__global__ __launch_bounds__(256) void gate_topk(const float* __restrict__ x2,
                                                 const float* __restrict__ gw,
                                                 int* __restrict__ cnt, int* __restrict__ lists,
                                                 float* __restrict__ wsl) {
  int t = blockIdx.x, tid = threadIdx.x;
  const float* xr = x2 + (long)t * cH;
  float a[8] = {0, 0, 0, 0, 0, 0, 0, 0};
  for (int h = tid; h < cH; h += 256) {
    float xv = xr[h];
    float4 g0 = *(const float4*)(gw + h * 8);
    float4 g1 = *(const float4*)(gw + h * 8 + 4);
    a[0] += xv * g0.x; a[1] += xv * g0.y; a[2] += xv * g0.z; a[3] += xv * g0.w;
    a[4] += xv * g1.x; a[5] += xv * g1.y; a[6] += xv * g1.z; a[7] += xv * g1.w;
  }
  __shared__ float red[256 * 8];
#pragma unroll
  for (int e = 0; e < 8; ++e) red[tid * 8 + e] = a[e];
  __syncthreads();
  for (int s = 128; s > 0; s >>= 1) {
    if (tid < s)
#pragma unroll
      for (int e = 0; e < 8; ++e) red[tid * 8 + e] += red[(tid + s) * 8 + e];
    __syncthreads();
  }
  if (tid == 0) {
    float lg[8];
#pragma unroll
    for (int e = 0; e < 8; ++e) lg[e] = red[e];
    int i0 = 0;
#pragma unroll
    for (int e = 1; e < 8; ++e) if (lg[e] > lg[i0]) i0 = e;
    int i1 = -1;
#pragma unroll
    for (int e = 0; e < 8; ++e)
      if (e != i0 && (i1 < 0 || lg[e] > lg[i1])) i1 = e;
    float e1 = expf(lg[i1] - lg[i0]);
    float w0 = 1.f / (1.f + e1);
    float w1 = e1 / (1.f + e1);
    int p0 = atomicAdd(&cnt[i0], 1);
    lists[i0 * cT + p0] = 2 * t;
    int p1 = atomicAdd(&cnt[i1], 1);
    lists[i1 * cT + p1] = 2 * t + 1;
    wsl[2 * t] = w0;
    wsl[2 * t + 1] = w1;
  }
}

// ====================================================================
// MoE (post-gate: continuous path, bf16 MFMA OK)
// Software-pipelined: double-buffered LDS + 1-step register prefetch,
// ONE barrier per K-step. Numerics identical to the serial version.
// ====================================================================
__device__ __forceinline__ void mfma_step(const short* As, const short* Bs,
                                          floatx4 acc[4][4], int wm, int wn, int lane) {
  int lr = lane & 15, qd = lane >> 4;
  shortx8 af[4], bfr[4];
#pragma unroll
  for (int i = 0; i < 4; ++i)
    af[i] = *(const shortx8*)&As[(wm * 64 + i * 16 + lr) * LDSK + qd * 8];
#pragma unroll
  for (int j = 0; j < 4; ++j)
    bfr[j] = *(const shortx8*)&Bs[(wn * 64 + j * 16 + lr) * LDSK + qd * 8];
#pragma unroll
  for (int i = 0; i < 4; ++i)
#pragma unroll
    for (int j = 0; j < 4; ++j)
      acc[i][j] = __builtin_amdgcn_mfma_f32_16x16x32_bf16(af[i], bfr[j], acc[i][j], 0, 0, 0);
}

__global__ __launch_bounds__(256, 2) void moe_gemm1(const float* __restrict__ x2,
                                                    const float* __restrict__ w1,
                                                    const float* __restrict__ w3,
                                                    const int* __restrict__ cnt,
                                                    const int* __restrict__ lists,
                                                    const float* __restrict__ wsl,
                                                    short* __restrict__ z) {
  int e = blockIdx.z, mt = blockIdx.y, n0 = blockIdx.x * 128;
  int c = cnt[e];
  if (mt * 128 >= c) return;
  __shared__ int ent[128];
  __shared__ float wrt[128];
  int tid = threadIdx.x;
  if (tid < 128) {
    int r = mt * 128 + tid;
    int en = (r < c) ? lists[e * cT + r] : 0;
    ent[tid] = en;
    wrt[tid] = (r < c) ? wsl[en] : 0.f;
  }
  __syncthreads();
  __shared__ __align__(16) short As[2][128 * LDSK];
  __shared__ __align__(16) short Bs1[2][128 * LDSK];
  __shared__ __align__(16) short Bs3[2][128 * LDSK];

  // per-thread A source pointers (4 chunks: row m = idx>>3, 16B col chunk idx&7)
  const float* ap[4];
#pragma unroll
  for (int it = 0; it < 4; ++it) {
    int idx = tid + it * 256;
    ap[it] = x2 + (long)(ent[idx >> 3] >> 1) * cH + (idx & 7) * 4;
  }
  // per-thread B column pointers (16 strided rows starting at bkg*16)
  int bn = tid & 127, bkg = tid >> 7;
  const float* b1p = w1 + (long)e * cH * cF + (long)(bkg * 16) * cF + n0 + bn;
  const float* b3p = w3 + (long)e * cH * cF + (long)(bkg * 16) * cF + n0 + bn;

  float4 ra[4];
  float rb1[16], rb3[16];

#define G1_LOAD(k0)                                                        \
  {                                                                        \
    _Pragma("unroll") for (int it = 0; it < 4; ++it)                       \
        ra[it] = *(const float4*)(ap[it] + (k0));                          \
    _Pragma("unroll") for (int i = 0; i < 16; ++i)                         \
        rb1[i] = b1p[((k0) + i) * cF];                                     \
    _Pragma("unroll") for (int i = 0; i < 16; ++i)                         \
        rb3[i] = b3p[((k0) + i) * cF];                                     \
  }

#define G1_CVTW(buf)                                                       \
  {                                                                        \
    _Pragma("unroll") for (int it = 0; it < 4; ++it) {                     \
      int idx = tid + it * 256;                                            \
      int m = idx >> 3, c4 = idx & 7;                                      \
      *(shortx4*)&As[buf][m * LDSK + c4 * 4] =                             \
          f2bf4(ra[it].x, ra[it].y, ra[it].z, ra[it].w);                   \
    }                                                                      \
    _Pragma("unroll") for (int w = 0; w < 4; ++w)                          \
        *(shortx4*)&Bs1[buf][bn * LDSK + bkg * 16 + w * 4] =               \
            f2bf4(rb1[4 * w], rb1[4 * w + 1], rb1[4 * w + 2], rb1[4 * w + 3]); \
    _Pragma("unroll") for (int w = 0; w < 4; ++w)                          \
        *(shortx4*)&Bs3[buf][bn * LDSK + bkg * 16 + w * 4] =               \
            f2bf4(rb3[4 * w], rb3[4 * w + 1], rb3[4 * w + 2], rb3[4 * w + 3]); \
  }

  floatx4 a1[4][4] = {}, a3[4][4] = {};
  int lane = tid & 63, wvv = tid >> 6, wm = wvv >> 1, wn = wvv & 1;

  constexpr int NS = cH / 32;  // 64 K-steps
  G1_LOAD(0);
  G1_CVTW(0);
  G1_LOAD(32);
  __syncthreads();
  for (int t = 0; t < NS; ++t) {
    int buf = t & 1;
    mfma_step(As[buf], Bs1[buf], a1, wm, wn, lane);
    mfma_step(As[buf], Bs3[buf], a3, wm, wn, lane);
    if (t + 1 < NS) {
      G1_CVTW(buf ^ 1);                       // write k=t+1 into other buffer
      if (t + 2 < NS) G1_LOAD((t + 2) * 32);  // prefetch k=t+2 into regs
    }
    __syncthreads();
  }
#undef G1_LOAD
#undef G1_CVTW

  int lr = lane & 15, qd = lane >> 4;
  int rlim = c - mt * 128;
#pragma unroll
  for (int i = 0; i < 4; ++i)
#pragma unroll
    for (int r = 0; r < 4; ++r) {
      int row = wm * 64 + i * 16 + qd * 4 + r;
      if (row < rlim) {
        long zb = (long)ent[row] * cF + n0;
        float wgt = wrt[row];
#pragma unroll
        for (int j = 0; j < 4; ++j) {
          float h1 = a1[i][j][r], h3 = a3[i][j][r];
          float sv = h1 / (1.f + __expf(-h1));
          z[zb + wn * 64 + j * 16 + lr] = (short)f2bf(wgt * sv * h3);
        }
      }
    }
}

__global__ __launch_bounds__(256, 2) void moe_gemm2(const short* __restrict__ z,
                                                    const float* __restrict__ w2,
                                                    const int* __restrict__ cnt,
                                                    const int* __restrict__ lists,
                                                    float* __restrict__ eo) {
  int e = blockIdx.z, mt = blockIdx.y, n0 = blockIdx.x * 128;
  int c = cnt[e];
  if (mt * 128 >= c) return;
  __shared__ int ent[128];
  int tid = threadIdx.x;
  if (tid < 128) {
    int r = mt * 128 + tid;
    ent[tid] = (r < c) ? lists[e * cT + r] : 0;
  }
  __syncthreads();
  __shared__ __align__(16) short As[2][128 * LDSK];
  __shared__ __align__(16) short Bs[2][128 * LDSK];

  // per-thread A source pointers (2 chunks: row m = idx>>2, 16B col chunk idx&3)
  const short* ap[2];
#pragma unroll
  for (int it = 0; it < 2; ++it) {
    int idx = tid + it * 256;
    ap[it] = z + (long)ent[idx >> 2] * cF + (idx & 3) * 8;
  }
  int bn = tid & 127, bkg = tid >> 7;
  const float* bp = w2 + (long)e * cF * cH + (long)(bkg * 16) * cH + n0 + bn;

  shortx8 raz[2];
  float rb[16];

#define G2_LOAD(k0)                                                        \
  {                                                                        \
    _Pragma("unroll") for (int it = 0; it < 2; ++it)                       \
        raz[it] = *(const shortx8*)(ap[it] + (k0));                        \
    _Pragma("unroll") for (int i = 0; i < 16; ++i)                         \
        rb[i] = bp[((k0) + i) * cH];                                       \
  }

#define G2_CVTW(buf)                                                       \
  {                                                                        \
    _Pragma("unroll") for (int it = 0; it < 2; ++it) {                     \
      int idx = tid + it * 256;                                            \
      int m = idx >> 2, c8 = idx & 3;                                      \
      *(shortx8*)&As[buf][m * LDSK + c8 * 8] = raz[it];                    \
    }                                                                      \
    _Pragma("unroll") for (int w = 0; w < 4; ++w)                          \
        *(shortx4*)&Bs[buf][bn * LDSK + bkg * 16 + w * 4] =                \
            f2bf4(rb[4 * w], rb[4 * w + 1], rb[4 * w + 2], rb[4 * w + 3]); \
  }

  floatx4 acc[4][4] = {};
  int lane = tid & 63, wvv = tid >> 6, wm = wvv >> 1, wn = wvv & 1;

  constexpr int NS = cF / 32;  // 128 K-steps
  G2_LOAD(0);
  G2_CVTW(0);
  G2_LOAD(32);
  __syncthreads();
  for (int t = 0; t < NS; ++t) {
    int buf = t & 1;
    mfma_step(As[buf], Bs[buf], acc, wm, wn, lane);
    if (t + 1 < NS) {
      G2_CVTW(buf ^ 1);
      if (t + 2 < NS) G2_LOAD((t + 2) * 32);
    }
    __syncthreads();
  }
#undef G2_LOAD
#undef G2_CVTW

  int lr = lane & 15, qd = lane >> 4;
  int rlim = c - mt * 128;
#pragma unroll
  for (int i = 0; i < 4; ++i)
#pragma unroll
    for (int r = 0; r < 4; ++r) {
      int row = wm * 64 + i * 16 + qd * 4 + r;
      if (row < rlim) {
        long ob = (long)ent[row] * cH + n0;
#pragma unroll
        for (int j = 0; j < 4; ++j) eo[ob + wn * 64 + j * 16 + lr] = acc[i][j][r];
      }
    }
}

// ---------- final: out = h + eo[2t] + eo[2t+1] ----------
__global__ __launch_bounds__(256) void final_add(const float* __restrict__ h,
                                                 const float* __restrict__ eo,
                                                 float* __restrict__ out) {
  int t = blockIdx.x, tid = threadIdx.x;
  const float* hr = h + (long)t * cH;
  const float* e0 = eo + (long)(2 * t) * cH;
  const float* e1 = eo + (long)(2 * t + 1) * cH;
  float* orow = out + (long)t * cH;
#pragma unroll
  for (int it = 0; it < 2; ++it) {
    int i = tid * 4 + it * 1024;
    float4 a = *(const float4*)(hr + i);
    float4 b = *(const float4*)(e0 + i);
    float4 c = *(const float4*)(e1 + i);
    float4 r;
    r.x = a.x + b.x + c.x;
    r.y = a.y + b.y + c.y;
    r.z = a.z + b.z + c.z;
    r.w = a.w + b.w + c.w;
    *(float4*)(orow + i) = r;
  }
}

extern "C" void kernel_launch(void* const* d_in, const int* in_sizes, int n_in,
                              void* d_out, int out_size, void* d_ws, size_t ws_size,
                              hipStream_t stream) {
  const float* hidden = (const float*)d_in[0];
  const int* amask = (const int*)d_in[1];
  const int* posid = (const int*)d_in[2];
  const float* ln1w = (const float*)d_in[3];
  const float* ln1b = (const float*)d_in[4];
  const float* ln2w = (const float*)d_in[5];
  const float* ln2b = (const float*)d_in[6];
  const float* wq = (const float*)d_in[7];
  const float* bq = (const float*)d_in[8];
  const float* wk = (const float*)d_in[9];
  const float* bk = (const float*)d_in[10];
  const float* wv = (const float*)d_in[11];
  const float* bv = (const float*)d_in[12];
  const float* wo = (const float*)d_in[13];
  const float* bo = (const float*)d_in[14];
  const float* gw = (const float*)d_in[15];
  const float* w1 = (const float*)d_in[16];
  const float* w2 = (const float*)d_in[17];
  const float* w3 = (const float*)d_in[18];
  float* out = (float*)d_out;

  // workspace layout (~120.1 MiB total)
  char* ws = (char*)d_ws;
  const size_t MB = 1024 * 1024;
  float* x = (float*)(ws);                 // 0..16M   (LN1 out; later attn)
  float* q = (float*)(ws + 16 * MB);       // 16..32M  (later hbuf)
  float* k = (float*)(ws + 32 * MB);       // 32..36M
  float* v = (float*)(ws + 36 * MB);       // 36..40M
  float* sc = (float*)(ws + 40 * MB);      // 40..104M scores->probs in place
  float* attn = x;                         // alias (x dead after v-proj)
  float* hbuf = q;                         // alias (q dead after attention)
  float* x2 = sc;                          // 40..56M (scores dead)
  short* z = (short*)(ws + 56 * MB);       // 56..88M bf16
  float* eo = (float*)(ws + 88 * MB);      // 88..120M
  int* cnt = (int*)(ws + 120 * MB);
  int* lists = (int*)(ws + 120 * MB + 256);
  float* wsl = (float*)(ws + 120 * MB + 256 + (size_t)8 * cT * 4);

  dim3 blk(256);

  // 1) LN1
  ln_kernel<<<cT, blk, 0, stream>>>(hidden, ln1w, ln1b, x);
  // 2) QKV projections (fp32)
  gemm32<1><<<dim3(32, 32), blk, 0, stream>>>(x, wq, q, bq, nullptr, cH, cH, cNH * cHD, cNH * cHD);
  gemm32<1><<<dim3(8, 32), blk, 0, stream>>>(x, wk, k, bk, nullptr, cH, cH, cNKV * cHD, cNKV * cHD);
  gemm32<1><<<dim3(8, 32), blk, 0, stream>>>(x, wv, v, bv, nullptr, cH, cH, cNKV * cHD, cNKV * cHD);
  // 3) RoPE
  rope_kernel<<<(cT * cNH) / 4, blk, 0, stream>>>(q, posid, cNH);
  rope_kernel<<<(cT * cNKV) / 4, blk, 0, stream>>>(k, posid, cNKV);
  // 4) attention (fp32), per batch
  for (int b = 0; b < cB; ++b) {
    qk32<<<dim3(16, 16, cNH), blk, 0, stream>>>(q, k, sc, b);
    softmax32<<<cNH * cS, blk, 0, stream>>>(sc, amask, b);
    pv32<<<dim3(2, 16, cNH), blk, 0, stream>>>(sc, v, attn, b);
  }
  // 5) O-projection + residual -> h (fp32)
  gemm32<2><<<dim3(32, 32), blk, 0, stream>>>(attn, wo, hbuf, bo, hidden, cH, cH, cH, cH);
  // 6) LN2 -> x2
  ln_kernel<<<cT, blk, 0, stream>>>(hbuf, ln2w, ln2b, x2);
  // 7) routing (fp32-exact decisions)
  zero_cnt<<<1, 64, 0, stream>>>(cnt);
  gate_topk<<<cT, blk, 0, stream>>>(x2, gw, cnt, lists, wsl);
  // 8) MoE (bf16 MFMA, software-pipelined)
  moe_gemm1<<<dim3(cF / 128, cT / 128, 8), blk, 0, stream>>>(x2, w1, w3, cnt, lists, wsl, z);
  moe_gemm2<<<dim3(cH / 128, cT / 128, 8), blk, 0, stream>>>(z, w2, cnt, lists, eo);
  // 9) out = h + moe
  final_add<<<cT, blk, 0, stream>>>(hbuf, eo, out);
  (void)in_sizes; (void)n_in; (void)out_size; (void)ws_size;
}